// Round 5
// baseline (223.626 us; speedup 1.0000x reference)
//
#include <hip/hip_runtime.h>
#include <hip/hip_bf16.h>
#include <math.h>

// ---------------------------------------------------------------------------
// Neural3DHMM on MI355X (gfx950) — round 5
//   conv_k eliminated (f32->bf16 conversion fused into GEMM LDS staging)
//   gemm3 -> dedicated 128x128-tile lse_gemm_k with in-register LSE partials
//   8 launches: gemm1, gemm2, ln, trans(+plse), lse_gemm, lse_fin, empool, fwd
// ---------------------------------------------------------------------------

typedef __bf16 bf16_t;
typedef __bf16 bf16x8 __attribute__((ext_vector_type(8)));
typedef float  floatx4 __attribute__((ext_vector_type(4)));
typedef short  short8  __attribute__((ext_vector_type(8)));

#define S_TOT 2048
#define NT2 79     // ceil(10000/128)
#define LSE_LD 80  // padded row stride for Pmax/Psum [s][nb]

// ------------------------------ bf16 MFMA GEMM (batched, f32 sources) ------
// C[m][n] = sum_k A[m][k] * B[n][k]   (B always f32 row-major [Nrows x Kvalid])
// A: f32 (A32=1) or bf16 (A32=0). B rows >= Nrows and cols >= Kvalid -> 0.
// EPI 1: v=relu(c+bias[n]); store f32 C and bf16 Cbf
// EPI 2: v=relu(c+bias[n]) + addm[m][n]; store f32 C
struct GJob {
    const float*  Af;
    const bf16_t* Ab;
    int lda;
    const float* B; int ldb;
    int N, Nrows, K, Kvalid;
    float* C; int ldc;
    const float* bias; int nbias;
    const float* addm; int ldadd;
    bf16_t* Cbf; int ldcb;
};
struct GJobs { GJob j[4]; };

#define BM 64
#define BN 64
#define LDT 72

template<int EPI, int A32>
__global__ __launch_bounds__(256) void gemm_k(GJobs jobs) {
    GJob jb = jobs.j[blockIdx.z];
    const int m0 = blockIdx.x * BM;
    const int n0 = blockIdx.y * BN;
    if (n0 >= jb.N) return;

    __shared__ alignas(16) bf16_t As[BM * LDT];
    __shared__ alignas(16) bf16_t Bs[BN * LDT];
    const int tid  = threadIdx.x;
    const int lane = tid & 63, wave = tid >> 6;
    const int wm = (wave & 1) * 32, wn = (wave >> 1) * 32;
    const int sr = tid >> 2, scc = (tid & 3) * 16;
    const int qm = lane & 15, qk = (lane >> 4) * 8;

    floatx4 acc[2][2];
    floatx4 zf = {0.f, 0.f, 0.f, 0.f};
#pragma unroll
    for (int i = 0; i < 2; i++)
#pragma unroll
        for (int j = 0; j < 2; j++) acc[i][j] = zf;

    const bool brv = (n0 + sr) < jb.Nrows;

    for (int k0 = 0; k0 < jb.K; k0 += 64) {
        // ---- A staging ----
        if constexpr (A32) {
            const float* Ar = jb.Af + (size_t)(m0 + sr) * jb.lda + k0 + scc;
            alignas(16) bf16_t ta[16];
#pragma unroll
            for (int i = 0; i < 4; i++) {
                float4 f = ((const float4*)Ar)[i];
                ta[i * 4 + 0] = (bf16_t)f.x; ta[i * 4 + 1] = (bf16_t)f.y;
                ta[i * 4 + 2] = (bf16_t)f.z; ta[i * 4 + 3] = (bf16_t)f.w;
            }
            *(short8*)&As[sr * LDT + scc]     = *(short8*)&ta[0];
            *(short8*)&As[sr * LDT + scc + 8] = *(short8*)&ta[8];
        } else {
            const bf16_t* Ar = jb.Ab + (size_t)(m0 + sr) * jb.lda + k0 + scc;
            *(short8*)&As[sr * LDT + scc]     = *(const short8*)&Ar[0];
            *(short8*)&As[sr * LDT + scc + 8] = *(const short8*)&Ar[8];
        }
        // ---- B staging (f32, row/col guarded) ----
        {
            const float* Br = jb.B + (size_t)(n0 + sr) * jb.ldb + k0 + scc;
            alignas(16) bf16_t tb[16];
#pragma unroll
            for (int i = 0; i < 4; i++) {
                int c4 = k0 + scc + i * 4;
                float4 f = {0.f, 0.f, 0.f, 0.f};
                if (brv && c4 < jb.Kvalid) f = *(const float4*)&Br[i * 4];
                tb[i * 4 + 0] = (bf16_t)f.x; tb[i * 4 + 1] = (bf16_t)f.y;
                tb[i * 4 + 2] = (bf16_t)f.z; tb[i * 4 + 3] = (bf16_t)f.w;
            }
            *(short8*)&Bs[sr * LDT + scc]     = *(short8*)&tb[0];
            *(short8*)&Bs[sr * LDT + scc + 8] = *(short8*)&tb[8];
        }
        __syncthreads();
#pragma unroll
        for (int kk = 0; kk < 2; kk++) {
            int qo = kk * 32 + qk;
            bf16x8 a[2], b[2];
            a[0] = *(const bf16x8*)&As[(wm + qm) * LDT + qo];
            a[1] = *(const bf16x8*)&As[(wm + 16 + qm) * LDT + qo];
            b[0] = *(const bf16x8*)&Bs[(wn + qm) * LDT + qo];
            b[1] = *(const bf16x8*)&Bs[(wn + 16 + qm) * LDT + qo];
#pragma unroll
            for (int mi = 0; mi < 2; mi++)
#pragma unroll
                for (int ni = 0; ni < 2; ni++)
                    acc[mi][ni] = __builtin_amdgcn_mfma_f32_16x16x32_bf16(a[mi], b[ni], acc[mi][ni], 0, 0, 0);
        }
        __syncthreads();
    }

    const int cl = lane & 15, rq = (lane >> 4) * 4;
#pragma unroll
    for (int mi = 0; mi < 2; mi++)
#pragma unroll
        for (int ni = 0; ni < 2; ni++)
#pragma unroll
            for (int r = 0; r < 4; r++) {
                int gm = m0 + wm + mi * 16 + rq + r;
                int gn = n0 + wn + ni * 16 + cl;
                if (gn < jb.N) {
                    float bv = (gn < jb.nbias) ? jb.bias[gn] : 0.f;
                    float v = fmaxf(acc[mi][ni][r] + bv, 0.f);
                    if constexpr (EPI == 1) {
                        jb.C[(size_t)gm * jb.ldc + gn] = v;
                        jb.Cbf[(size_t)gm * jb.ldcb + gn] = (bf16_t)v;
                    } else {
                        jb.C[(size_t)gm * jb.ldc + gn] = v + jb.addm[(size_t)gm * jb.ldadd + gn];
                    }
                }
            }
}

// ------------------------------ layernorm (batched, praw fused) ------------
struct LJob {
    const float* h; int ld, dout;
    const float* g; const float* beta;
    float* of32; int ldo;
    bf16_t* obf; int ldob; int padN;
    const float* wo; const float* bo; float* praw;
};
struct LJobs { LJob j[4]; };

__global__ __launch_bounds__(256) void ln_k(LJobs jobs) {
    LJob jb = jobs.j[blockIdx.y];
    __shared__ float red[256];
    int row = blockIdx.x, t = threadIdx.x;
    float hv = (t < jb.dout) ? jb.h[(size_t)row * jb.ld + t] : 0.f;
    red[t] = hv;
    __syncthreads();
#pragma unroll
    for (int s = 128; s > 0; s >>= 1) { if (t < s) red[t] += red[t + s]; __syncthreads(); }
    float mu = red[0] / jb.dout;
    __syncthreads();
    float d = (t < jb.dout) ? (hv - mu) : 0.f;
    red[t] = d * d;
    __syncthreads();
#pragma unroll
    for (int s = 128; s > 0; s >>= 1) { if (t < s) red[t] += red[t + s]; __syncthreads(); }
    float var = red[0] / jb.dout;
    float rstd = rsqrtf(var + 1e-5f);
    float y = 0.f;
    if (t < jb.dout) {
        y = d * rstd * jb.g[t] + jb.beta[t];
        if (jb.of32) jb.of32[(size_t)row * jb.ldo + t] = y;
        if (jb.obf)  jb.obf[(size_t)row * jb.ldob + t] = (bf16_t)y;
    } else if (jb.obf && t < jb.padN) {
        jb.obf[(size_t)row * jb.ldob + t] = (bf16_t)0.f;
    }
    if (jb.wo) {
        __syncthreads();
        red[t] = (t < jb.dout) ? y * jb.wo[t] : 0.f;
        __syncthreads();
#pragma unroll
        for (int s = 128; s > 0; s >>= 1) { if (t < s) red[t] += red[t + s]; __syncthreads(); }
        if (t == 0) jb.praw[row] = red[0] + jb.bo[0];
    }
}

// --------- sparse transition (7 neighbors) + fused prior logsumexp ---------
__global__ __launch_bounds__(256) void trans_k(const float* __restrict__ hin,
                                               const float* __restrict__ hout,
                                               float* __restrict__ tr,
                                               const float* __restrict__ praw,
                                               float* __restrict__ plse)
{
    __shared__ float red[256];
    if (blockIdx.x == 512) {
        int t = threadIdx.x;
        float v[8];
        float m = -INFINITY;
#pragma unroll
        for (int i = 0; i < 8; i++) { v[i] = praw[t * 8 + i]; m = fmaxf(m, v[i]); }
        red[t] = m;
        __syncthreads();
#pragma unroll
        for (int s = 128; s > 0; s >>= 1) { if (t < s) red[t] = fmaxf(red[t], red[t + s]); __syncthreads(); }
        float M = red[0];
        __syncthreads();
        float ss = 0.f;
#pragma unroll
        for (int i = 0; i < 8; i++) ss += __expf(v[i] - M);
        red[t] = ss;
        __syncthreads();
#pragma unroll
        for (int s = 128; s > 0; s >>= 1) { if (t < s) red[t] += red[t + s]; __syncthreads(); }
        if (t == 0) plse[0] = M + __logf(red[0]);
        return;
    }
    const int OFFS[7] = {0, 1, -1, 16, -16, 256, 512};
    int j = blockIdx.x * 4 + (threadIdx.x >> 6);
    int lane = threadIdx.x & 63;
    float4 a = ((const float4*)(hin + (size_t)j * 256))[lane];
    float d[7];
#pragma unroll
    for (int k = 0; k < 7; k++) {
        int i = j + OFFS[k];
        float pdot = 0.f;
        if ((unsigned)i < 2048u) {
            float4 b = ((const float4*)(hout + (size_t)i * 256))[lane];
            pdot = a.x * b.x + a.y * b.y + a.z * b.z + a.w * b.w;
        }
#pragma unroll
        for (int o = 32; o > 0; o >>= 1) pdot += __shfl_down(pdot, o);
        d[k] = pdot;
    }
    if (lane == 0) {
        float m = -INFINITY;
#pragma unroll
        for (int k = 0; k < 7; k++) { int i = j + OFFS[k]; if ((unsigned)i < 2048u) m = fmaxf(m, d[k]); }
        float ss = 0.f;
#pragma unroll
        for (int k = 0; k < 7; k++) { int i = j + OFFS[k]; if ((unsigned)i < 2048u) ss += __expf(d[k] - m); }
        float l = __logf(ss);
#pragma unroll
        for (int k = 0; k < 7; k++) {
            int i = j + OFFS[k];
            tr[(size_t)j * 8 + k] = ((unsigned)i < 2048u) ? (d[k] - m - l) : -INFINITY;
        }
        tr[(size_t)j * 8 + 7] = -INFINITY;
    }
}

// ------------- emission LSE GEMM: 128x128 tiles, in-register partials ------
// A = hemit bf16 [2048 x 128]; B = tok_emb f32 [10000 x 100] (guarded).
// Writes per-row (max, sumexp) partials over this 128-col tile.
#define LDT2 72
__global__ __launch_bounds__(256) void lse_gemm_k(
    const bf16_t* __restrict__ hemit, const float* __restrict__ tok_emb,
    float* __restrict__ Pmax, float* __restrict__ Psum)
{
    __shared__ alignas(16) bf16_t As[128 * LDT2];
    __shared__ alignas(16) bf16_t Bs[128 * LDT2];
    __shared__ float pmS[2][128];
    __shared__ float psS[2][128];
    const int mb = blockIdx.x * 128;
    const int n0 = blockIdx.y * 128;
    const int tid  = threadIdx.x;
    const int lane = tid & 63, wave = tid >> 6;
    const int wm = (wave & 1) * 64, wn = (wave >> 1) * 64;
    const int sr2 = tid >> 1, scc2 = (tid & 1) * 32;
    const int qm = lane & 15, qk = (lane >> 4) * 8;

    floatx4 acc[4][4];
    floatx4 zf = {0.f, 0.f, 0.f, 0.f};
#pragma unroll
    for (int i = 0; i < 4; i++)
#pragma unroll
        for (int j = 0; j < 4; j++) acc[i][j] = zf;

    const bool brv = (n0 + sr2) < 10000;
    const float* Brow = tok_emb + (size_t)(n0 + sr2) * 100;
    const bf16_t* Arow = hemit + (size_t)(mb + sr2) * 128;

#pragma unroll
    for (int k0 = 0; k0 < 128; k0 += 64) {
#pragma unroll
        for (int i = 0; i < 4; i++)
            *(short8*)&As[sr2 * LDT2 + scc2 + i * 8] = *(const short8*)&Arow[k0 + scc2 + i * 8];
        {
            alignas(16) bf16_t tb[32];
#pragma unroll
            for (int i = 0; i < 8; i++) {
                int c4 = k0 + scc2 + i * 4;
                float4 f = {0.f, 0.f, 0.f, 0.f};
                if (brv && c4 < 100) f = *(const float4*)&Brow[c4];
                tb[i * 4 + 0] = (bf16_t)f.x; tb[i * 4 + 1] = (bf16_t)f.y;
                tb[i * 4 + 2] = (bf16_t)f.z; tb[i * 4 + 3] = (bf16_t)f.w;
            }
#pragma unroll
            for (int i = 0; i < 4; i++)
                *(short8*)&Bs[sr2 * LDT2 + scc2 + i * 8] = *(short8*)&tb[i * 8];
        }
        __syncthreads();
#pragma unroll
        for (int kk = 0; kk < 2; kk++) {
            int qo = kk * 32 + qk;
            bf16x8 a[4], b[4];
#pragma unroll
            for (int mi = 0; mi < 4; mi++) a[mi] = *(const bf16x8*)&As[(wm + mi * 16 + qm) * LDT2 + qo];
#pragma unroll
            for (int ni = 0; ni < 4; ni++) b[ni] = *(const bf16x8*)&Bs[(wn + ni * 16 + qm) * LDT2 + qo];
#pragma unroll
            for (int mi = 0; mi < 4; mi++)
#pragma unroll
                for (int ni = 0; ni < 4; ni++)
                    acc[mi][ni] = __builtin_amdgcn_mfma_f32_16x16x32_bf16(a[mi], b[ni], acc[mi][ni], 0, 0, 0);
        }
        __syncthreads();
    }

    // per-row (max, sumexp) over this wave's 64 cols, shuffle-reduced
    const int cl = lane & 15, rq = (lane >> 4) * 4;
    const int half = wn >> 6;
#pragma unroll
    for (int mi = 0; mi < 4; mi++) {
#pragma unroll
        for (int r = 0; r < 4; r++) {
            float mm = -INFINITY;
#pragma unroll
            for (int ni = 0; ni < 4; ni++) {
                int gcol = n0 + wn + ni * 16 + cl;
                if (gcol < 10000) mm = fmaxf(mm, acc[mi][ni][r]);
            }
            mm = fmaxf(mm, __shfl_xor(mm, 1));
            mm = fmaxf(mm, __shfl_xor(mm, 2));
            mm = fmaxf(mm, __shfl_xor(mm, 4));
            mm = fmaxf(mm, __shfl_xor(mm, 8));
            float ss = 0.f;
#pragma unroll
            for (int ni = 0; ni < 4; ni++) {
                int gcol = n0 + wn + ni * 16 + cl;
                if (gcol < 10000) ss += __expf(acc[mi][ni][r] - mm);
            }
            ss += __shfl_xor(ss, 1);
            ss += __shfl_xor(ss, 2);
            ss += __shfl_xor(ss, 4);
            ss += __shfl_xor(ss, 8);
            if (cl == 0) {
                int row = wm + mi * 16 + rq + r;
                pmS[half][row] = mm;
                psS[half][row] = ss;
            }
        }
    }
    __syncthreads();
    if (tid < 128) {
        float ma = pmS[0][tid], mb2 = pmS[1][tid];
        float M = fmaxf(ma, mb2);
        float S = psS[0][tid] * __expf(ma - M) + psS[1][tid] * __expf(mb2 - M);
        Pmax[(size_t)(mb + tid) * LSE_LD + blockIdx.y] = M;
        Psum[(size_t)(mb + tid) * LSE_LD + blockIdx.y] = S;
    }
}

// --------------------- emission logsumexp finalize (wave/state) ------------
__global__ __launch_bounds__(256) void lse_fin_k(const float* __restrict__ Pmax,
                                                 const float* __restrict__ Psum,
                                                 float* __restrict__ lse)
{
    int s = (blockIdx.x * 256 + threadIdx.x) >> 6;   // one wave per state
    int lane = threadIdx.x & 63;
    const float* pm = Pmax + (size_t)s * LSE_LD;
    const float* ps = Psum + (size_t)s * LSE_LD;
    float pv[2], sv[2];
    float m = -INFINITY;
#pragma unroll
    for (int i = 0; i < 2; i++) {
        int nb = i * 64 + lane;
        bool ok = nb < NT2;
        pv[i] = ok ? pm[nb] : -INFINITY;
        sv[i] = ok ? ps[nb] : 0.f;
        m = fmaxf(m, pv[i]);
    }
#pragma unroll
    for (int o = 1; o < 64; o <<= 1) m = fmaxf(m, __shfl_xor(m, o));
    float ss = 0.f;
#pragma unroll
    for (int i = 0; i < 2; i++) if (sv[i] > 0.f) ss += sv[i] * __expf(pv[i] - m);
#pragma unroll
    for (int o = 1; o < 64; o <<= 1) ss += __shfl_xor(ss, o);
    if (lane == 0) lse[s] = m + __logf(ss);
}

// ---- fused: em tile MFMA (12 tokens x 256 states) + 5x5 pool + emis -------
#define ELDT 136
__global__ __launch_bounds__(256) void empool_k(
    const float* __restrict__ tok_emb, const int* __restrict__ stories,
    const bf16_t* __restrict__ hemit, const float* __restrict__ lse,
    float* __restrict__ emis)
{
    __shared__ alignas(16) bf16_t As[16 * ELDT];
    __shared__ float Cs[16][260];
    __shared__ float sm2[256];
    __shared__ int stok[12];
    const int bt = blockIdx.x, z = blockIdx.y, t = threadIdx.x;
    if (t < 12) stok[t] = stories[bt * 12 + t];
    __syncthreads();
    {
        int row = t >> 4, c0 = (t & 15) * 8;
        int tok = (row < 12) ? stok[row] : 10000;
        const float* src = tok_emb + (size_t)tok * 100;
#pragma unroll
        for (int c = 0; c < 8; c++) {
            int cc = c0 + c;
            float v = (tok < 10000 && cc < 100) ? src[cc] : 0.f;
            As[row * ELDT + cc] = (bf16_t)v;
        }
    }
    __syncthreads();

    const int lane = t & 63, wave = t >> 6;
    const int qm = lane & 15, q = lane >> 4;
    floatx4 acc[4];
    floatx4 zf = {0.f, 0.f, 0.f, 0.f};
#pragma unroll
    for (int j = 0; j < 4; j++) acc[j] = zf;

#pragma unroll
    for (int kk = 0; kk < 4; kk++) {
        bf16x8 a = *(const bf16x8*)&As[qm * ELDT + kk * 32 + q * 8];
#pragma unroll
        for (int j = 0; j < 4; j++) {
            int nrow = z * 256 + (wave * 4 + j) * 16 + qm;
            bf16x8 b = *(const bf16x8*)&hemit[(size_t)nrow * 128 + kk * 32 + q * 8];
            acc[j] = __builtin_amdgcn_mfma_f32_16x16x32_bf16(a, b, acc[j], 0, 0, 0);
        }
    }
    {
        const int cl = lane & 15, rq = (lane >> 4) * 4;
#pragma unroll
        for (int j = 0; j < 4; j++) {
            int n = (wave * 4 + j) * 16 + cl;
            float ls = lse[z * 256 + n];
#pragma unroll
            for (int r = 0; r < 4; r++)
                Cs[rq + r][n] = acc[j][r] - ls;
        }
    }
    __syncthreads();

    const int a = t >> 4, b = t & 15;
    float accum = 0.f;
    for (int l = 0; l < 12; l++) {
        float m = -INFINITY;
#pragma unroll
        for (int d = -2; d <= 2; d++) {
            int bb = b + d; bb = bb < 0 ? 0 : (bb > 15 ? 15 : bb);
            m = fmaxf(m, Cs[l][a * 16 + bb]);
        }
        float ss = 0.f;
#pragma unroll
        for (int d = -2; d <= 2; d++) {
            int bb = b + d; bb = bb < 0 ? 0 : (bb > 15 ? 15 : bb);
            ss += __expf(Cs[l][a * 16 + bb] - m);
        }
        sm2[t] = m + __logf(ss);
        __syncthreads();
        float m2 = -INFINITY;
#pragma unroll
        for (int d = -2; d <= 2; d++) {
            int aa = a + d; aa = aa < 0 ? 0 : (aa > 15 ? 15 : aa);
            m2 = fmaxf(m2, sm2[aa * 16 + b]);
        }
        float s2 = 0.f;
#pragma unroll
        for (int d = -2; d <= 2; d++) {
            int aa = a + d; aa = aa < 0 ? 0 : (aa > 15 ? 15 : aa);
            s2 += __expf(sm2[aa * 16 + b] - m2);
        }
        if (stok[l] < 10000) accum += m2 + __logf(s2) - 3.2188758248682006f;  // log(25)
        __syncthreads();
    }
    emis[(size_t)bt * S_TOT + (size_t)z * 256 + t] = accum;
}

// --------------------- HMM forward recursion -------------------------------
__global__ __launch_bounds__(1024) void fwd_k(const float* __restrict__ emm,
                                              const float* __restrict__ praw,
                                              const float* __restrict__ plse,
                                              const float* __restrict__ tr,
                                              float* __restrict__ out)
{
    const int OFFS[7] = {0, 1, -1, 16, -16, 256, 512};
    __shared__ float sc[2][S_TOT];
    int b = blockIdx.x, t = threadIdx.x;
    float pl = plse[0];
    const float* eb = emm + (size_t)b * 16 * S_TOT;

    float e[2][16];
#pragma unroll
    for (int i = 0; i < 2; i++) {
        int j = i * 1024 + t;
#pragma unroll
        for (int tt = 0; tt < 16; tt++) e[i][tt] = eb[tt * S_TOT + j];
    }
    float trj[2][7];
#pragma unroll
    for (int i = 0; i < 2; i++) {
        int j = i * 1024 + t;
        float4 lo = ((const float4*)(tr + (size_t)j * 8))[0];
        float4 hi = ((const float4*)(tr + (size_t)j * 8))[1];
        trj[i][0] = lo.x; trj[i][1] = lo.y; trj[i][2] = lo.z; trj[i][3] = lo.w;
        trj[i][4] = hi.x; trj[i][5] = hi.y; trj[i][6] = hi.z;
    }
#pragma unroll
    for (int i = 0; i < 2; i++) {
        int j = i * 1024 + t;
        float v = e[i][0] + praw[j] - pl;
        sc[0][j] = v;
        out[(size_t)b * S_TOT + j] = v;
    }
    __syncthreads();
#pragma unroll
    for (int tt = 1; tt < 16; tt++) {
        int cur = tt & 1, prv = cur ^ 1;
#pragma unroll
        for (int i = 0; i < 2; i++) {
            int j = i * 1024 + t;
            float x[7];
            float m = -INFINITY;
#pragma unroll
            for (int k = 0; k < 7; k++) {
                int ii = j + OFFS[k];
                ii = ii < 0 ? 0 : (ii > 2047 ? 2047 : ii);
                x[k] = trj[i][k] + sc[prv][ii];
                m = fmaxf(m, x[k]);
            }
            float ss = 0.f;
#pragma unroll
            for (int k = 0; k < 7; k++) ss += __expf(x[k] - m);
            float v = e[i][tt] + m + __logf(ss);
            sc[cur][j] = v;
            out[(size_t)tt * (8 * S_TOT) + (size_t)b * S_TOT + j] = v;
        }
        __syncthreads();
    }
}

// ---------------------------------------------------------------------------
extern "C" void kernel_launch(void* const* d_in, const int* in_sizes, int n_in,
                              void* d_out, int out_size, void* d_ws, size_t ws_size,
                              hipStream_t stream)
{
    (void)in_sizes; (void)n_in; (void)out_size; (void)ws_size;
    const float* state_emb  = (const float*)d_in[0];
    const float* tok_emb    = (const float*)d_in[1];
    const float* start_w1   = (const float*)d_in[2];
    const float* start_b1   = (const float*)d_in[3];
    const float* start_w2   = (const float*)d_in[4];
    const float* start_b2   = (const float*)d_in[5];
    const float* start_g    = (const float*)d_in[6];
    const float* start_beta = (const float*)d_in[7];
    const float* start_wo   = (const float*)d_in[8];
    const float* start_bo   = (const float*)d_in[9];
    const float* tin_w1     = (const float*)d_in[10];
    const float* tin_b1     = (const float*)d_in[11];
    const float* tin_w2     = (const float*)d_in[12];
    const float* tin_b2     = (const float*)d_in[13];
    const float* tin_g      = (const float*)d_in[14];
    const float* tin_beta   = (const float*)d_in[15];
    const float* tout_w1    = (const float*)d_in[16];
    const float* tout_b1    = (const float*)d_in[17];
    const float* tout_w2    = (const float*)d_in[18];
    const float* tout_b2    = (const float*)d_in[19];
    const float* tout_g     = (const float*)d_in[20];
    const float* tout_beta  = (const float*)d_in[21];
    const float* emit_w1    = (const float*)d_in[22];
    const float* emit_b1    = (const float*)d_in[23];
    const float* emit_w2    = (const float*)d_in[24];
    const float* emit_b2    = (const float*)d_in[25];
    const float* emit_g     = (const float*)d_in[26];
    const float* emit_beta  = (const float*)d_in[27];
    const int*   stories    = (const int*)d_in[28];
    float* out = (float*)d_out;

    char* base = (char*)d_ws;
    size_t off = 0;
    auto carve = [&](size_t bytes) -> char* {
        char* r = base + off;
        off = (off + bytes + 255) & ~(size_t)255;
        return r;
    };

    // ---- persistent region ----
    bf16_t* hemit = (bf16_t*)carve((size_t)2048 * 128 * 2);
    float*  hin   = (float*)carve((size_t)2048 * 256 * 4);
    float*  hout  = (float*)carve((size_t)2048 * 256 * 4);
    float*  praw  = (float*)carve((size_t)2048 * 4);
    float*  plse  = (float*)carve(256);
    float*  trans = (float*)carve((size_t)2048 * 8 * 4);
    float*  pmax  = (float*)carve((size_t)2048 * LSE_LD * 4);
    float*  psum  = (float*)carve((size_t)2048 * LSE_LD * 4);
    float*  lse   = (float*)carve((size_t)2048 * 4);
    float*  emis  = (float*)carve((size_t)128 * 2048 * 4);

    // ---- overlay region: stage-1/2 temps (dead after ln_k) ----
    float*  x1f_s  = (float*)carve((size_t)2048 * 256 * 4);
    float*  x1f_i  = (float*)carve((size_t)2048 * 256 * 4);
    float*  x1f_o  = (float*)carve((size_t)2048 * 256 * 4);
    float*  x1f_e  = (float*)carve((size_t)2048 * 128 * 4);
    bf16_t* x1b_s  = (bf16_t*)carve((size_t)2048 * 256 * 2);
    bf16_t* x1b_i  = (bf16_t*)carve((size_t)2048 * 256 * 2);
    bf16_t* x1b_o  = (bf16_t*)carve((size_t)2048 * 256 * 2);
    bf16_t* x1b_e  = (bf16_t*)carve((size_t)2048 * 128 * 2);
    float*  htmp_s = (float*)carve((size_t)2048 * 256 * 4);
    float*  htmp_i = (float*)carve((size_t)2048 * 256 * 4);
    float*  htmp_o = (float*)carve((size_t)2048 * 256 * 4);
    float*  htmp_e = (float*)carve((size_t)2048 * 128 * 4);

    // 1. stage-1 batched GEMM: x1 = relu(state_emb @ W1^T + b1)  (A,B f32)
    GJobs g1;
    g1.j[0] = {state_emb, nullptr, 256, start_w1, 256, 256, 256, 256, 256, x1f_s, 256, start_b1, 256, nullptr, 0, x1b_s, 256};
    g1.j[1] = {state_emb, nullptr, 256, tin_w1,   256, 256, 256, 256, 256, x1f_i, 256, tin_b1,   256, nullptr, 0, x1b_i, 256};
    g1.j[2] = {state_emb, nullptr, 256, tout_w1,  256, 256, 256, 256, 256, x1f_o, 256, tout_b1,  256, nullptr, 0, x1b_o, 256};
    g1.j[3] = {state_emb, nullptr, 256, emit_w1,  256, 128, 100, 256, 256, x1f_e, 128, emit_b1,  100, nullptr, 0, x1b_e, 128};
    gemm_k<1, 1><<<dim3(32, 4, 4), 256, 0, stream>>>(g1);

    // 2. stage-2 batched GEMM: h = relu(x1 @ W2^T + b2) + x1  (A bf16, B f32)
    GJobs g2;
    g2.j[0] = {nullptr, x1b_s, 256, start_w2, 256, 256, 256, 256, 256, htmp_s, 256, start_b2, 256, x1f_s, 256, nullptr, 0};
    g2.j[1] = {nullptr, x1b_i, 256, tin_w2,   256, 256, 256, 256, 256, htmp_i, 256, tin_b2,   256, x1f_i, 256, nullptr, 0};
    g2.j[2] = {nullptr, x1b_o, 256, tout_w2,  256, 256, 256, 256, 256, htmp_o, 256, tout_b2,  256, x1f_o, 256, nullptr, 0};
    g2.j[3] = {nullptr, x1b_e, 128, emit_w2,  100, 128, 100, 128, 100, htmp_e, 128, emit_b2,  100, x1f_e, 128, nullptr, 0};
    gemm_k<2, 0><<<dim3(32, 4, 4), 256, 0, stream>>>(g2);

    // 3. batched LN (+ fused priors dot for start chain)
    LJobs lj;
    lj.j[0] = {htmp_s, 256, 256, start_g, start_beta, nullptr, 0, nullptr, 0, 0, start_wo, start_bo, praw};
    lj.j[1] = {htmp_i, 256, 256, tin_g,   tin_beta,   hin, 256, nullptr, 0, 0, nullptr, nullptr, nullptr};
    lj.j[2] = {htmp_o, 256, 256, tout_g,  tout_beta,  hout, 256, nullptr, 0, 0, nullptr, nullptr, nullptr};
    lj.j[3] = {htmp_e, 128, 100, emit_g,  emit_beta,  nullptr, 0, hemit, 128, 128, nullptr, nullptr, nullptr};
    ln_k<<<dim3(2048, 4), 256, 0, stream>>>(lj);

    // 4. transition log-softmax + prior LSE (fused, block 512)
    trans_k<<<513, 256, 0, stream>>>(hin, hout, trans, praw, plse);

    // 5. emission logsumexp over V=10000 (128x128 tiles) + finalize
    lse_gemm_k<<<dim3(16, NT2), 256, 0, stream>>>(hemit, tok_emb, pmax, psum);
    lse_fin_k<<<512, 256, 0, stream>>>(pmax, psum, lse);

    // 6. fused em-GEMM + pool + emis
    empool_k<<<dim3(128, 8), 256, 0, stream>>>(tok_emb, stories, hemit, lse, emis);

    // 7. forward recursion -> [T,B,S] output
    fwd_k<<<8, 1024, 0, stream>>>(emis, praw, plse, trans, out);
}

// Round 6
// 221.075 us; speedup vs baseline: 1.0115x; 1.0115x over previous
//
#include <hip/hip_runtime.h>
#include <hip/hip_bf16.h>
#include <math.h>

// ---------------------------------------------------------------------------
// Neural3DHMM on MI355X (gfx950) — round 6
//   lse_gemm_k v3: LDS-free, fragments loaded directly from global (L2-hot)
//   tok_emb pre-converted to padded bf16 once (tokconv_k, coalesced)
//   9 launches: tokconv, gemm1, gemm2, ln, trans(+plse), lse_gemm, lse_fin,
//               empool, fwd
// ---------------------------------------------------------------------------

typedef __bf16 bf16_t;
typedef __bf16 bf16x8 __attribute__((ext_vector_type(8)));
typedef float  floatx4 __attribute__((ext_vector_type(4)));
typedef short  short8  __attribute__((ext_vector_type(8)));

#define S_TOT 2048
#define NT2 79     // ceil(10000/128)
#define LSE_LD 80  // padded row stride for Pmax/Psum [s][nb]
#define VPAD 10112 // 79*128 rows in tok_bf

// --------------------- tok_emb f32 [10000x100] -> bf16 [10112x128] ---------
__global__ __launch_bounds__(256) void tokconv_k(const float* __restrict__ src,
                                                 bf16_t* __restrict__ dst) {
    int idx = blockIdx.x * 256 + threadIdx.x;
    int r = idx >> 7, c = idx & 127;
    float v = (r < 10000 && c < 100) ? src[r * 100 + c] : 0.f;
    dst[idx] = (bf16_t)v;
}

// ------------------------------ bf16 MFMA GEMM (batched, f32 sources) ------
struct GJob {
    const float*  Af;
    const bf16_t* Ab;
    int lda;
    const float* B; int ldb;
    int N, Nrows, K, Kvalid;
    float* C; int ldc;
    const float* bias; int nbias;
    const float* addm; int ldadd;
    bf16_t* Cbf; int ldcb;
};
struct GJobs { GJob j[4]; };

#define BM 64
#define BN 64
#define LDT 72

template<int EPI, int A32>
__global__ __launch_bounds__(256) void gemm_k(GJobs jobs) {
    GJob jb = jobs.j[blockIdx.z];
    const int m0 = blockIdx.x * BM;
    const int n0 = blockIdx.y * BN;
    if (n0 >= jb.N) return;

    __shared__ alignas(16) bf16_t As[BM * LDT];
    __shared__ alignas(16) bf16_t Bs[BN * LDT];
    const int tid  = threadIdx.x;
    const int lane = tid & 63, wave = tid >> 6;
    const int wm = (wave & 1) * 32, wn = (wave >> 1) * 32;
    const int sr = tid >> 2, scc = (tid & 3) * 16;
    const int qm = lane & 15, qk = (lane >> 4) * 8;

    floatx4 acc[2][2];
    floatx4 zf = {0.f, 0.f, 0.f, 0.f};
#pragma unroll
    for (int i = 0; i < 2; i++)
#pragma unroll
        for (int j = 0; j < 2; j++) acc[i][j] = zf;

    const bool brv = (n0 + sr) < jb.Nrows;

    for (int k0 = 0; k0 < jb.K; k0 += 64) {
        if constexpr (A32) {
            const float* Ar = jb.Af + (size_t)(m0 + sr) * jb.lda + k0 + scc;
            alignas(16) bf16_t ta[16];
#pragma unroll
            for (int i = 0; i < 4; i++) {
                float4 f = ((const float4*)Ar)[i];
                ta[i * 4 + 0] = (bf16_t)f.x; ta[i * 4 + 1] = (bf16_t)f.y;
                ta[i * 4 + 2] = (bf16_t)f.z; ta[i * 4 + 3] = (bf16_t)f.w;
            }
            *(short8*)&As[sr * LDT + scc]     = *(short8*)&ta[0];
            *(short8*)&As[sr * LDT + scc + 8] = *(short8*)&ta[8];
        } else {
            const bf16_t* Ar = jb.Ab + (size_t)(m0 + sr) * jb.lda + k0 + scc;
            *(short8*)&As[sr * LDT + scc]     = *(const short8*)&Ar[0];
            *(short8*)&As[sr * LDT + scc + 8] = *(const short8*)&Ar[8];
        }
        {
            const float* Br = jb.B + (size_t)(n0 + sr) * jb.ldb + k0 + scc;
            alignas(16) bf16_t tb[16];
#pragma unroll
            for (int i = 0; i < 4; i++) {
                int c4 = k0 + scc + i * 4;
                float4 f = {0.f, 0.f, 0.f, 0.f};
                if (brv && c4 < jb.Kvalid) f = *(const float4*)&Br[i * 4];
                tb[i * 4 + 0] = (bf16_t)f.x; tb[i * 4 + 1] = (bf16_t)f.y;
                tb[i * 4 + 2] = (bf16_t)f.z; tb[i * 4 + 3] = (bf16_t)f.w;
            }
            *(short8*)&Bs[sr * LDT + scc]     = *(short8*)&tb[0];
            *(short8*)&Bs[sr * LDT + scc + 8] = *(short8*)&tb[8];
        }
        __syncthreads();
#pragma unroll
        for (int kk = 0; kk < 2; kk++) {
            int qo = kk * 32 + qk;
            bf16x8 a[2], b[2];
            a[0] = *(const bf16x8*)&As[(wm + qm) * LDT + qo];
            a[1] = *(const bf16x8*)&As[(wm + 16 + qm) * LDT + qo];
            b[0] = *(const bf16x8*)&Bs[(wn + qm) * LDT + qo];
            b[1] = *(const bf16x8*)&Bs[(wn + 16 + qm) * LDT + qo];
#pragma unroll
            for (int mi = 0; mi < 2; mi++)
#pragma unroll
                for (int ni = 0; ni < 2; ni++)
                    acc[mi][ni] = __builtin_amdgcn_mfma_f32_16x16x32_bf16(a[mi], b[ni], acc[mi][ni], 0, 0, 0);
        }
        __syncthreads();
    }

    const int cl = lane & 15, rq = (lane >> 4) * 4;
#pragma unroll
    for (int mi = 0; mi < 2; mi++)
#pragma unroll
        for (int ni = 0; ni < 2; ni++)
#pragma unroll
            for (int r = 0; r < 4; r++) {
                int gm = m0 + wm + mi * 16 + rq + r;
                int gn = n0 + wn + ni * 16 + cl;
                if (gn < jb.N) {
                    float bv = (gn < jb.nbias) ? jb.bias[gn] : 0.f;
                    float v = fmaxf(acc[mi][ni][r] + bv, 0.f);
                    if constexpr (EPI == 1) {
                        jb.C[(size_t)gm * jb.ldc + gn] = v;
                        jb.Cbf[(size_t)gm * jb.ldcb + gn] = (bf16_t)v;
                    } else {
                        jb.C[(size_t)gm * jb.ldc + gn] = v + jb.addm[(size_t)gm * jb.ldadd + gn];
                    }
                }
            }
}

// ------------------------------ layernorm (batched, praw fused) ------------
struct LJob {
    const float* h; int ld, dout;
    const float* g; const float* beta;
    float* of32; int ldo;
    bf16_t* obf; int ldob; int padN;
    const float* wo; const float* bo; float* praw;
};
struct LJobs { LJob j[4]; };

__global__ __launch_bounds__(256) void ln_k(LJobs jobs) {
    LJob jb = jobs.j[blockIdx.y];
    __shared__ float red[256];
    int row = blockIdx.x, t = threadIdx.x;
    float hv = (t < jb.dout) ? jb.h[(size_t)row * jb.ld + t] : 0.f;
    red[t] = hv;
    __syncthreads();
#pragma unroll
    for (int s = 128; s > 0; s >>= 1) { if (t < s) red[t] += red[t + s]; __syncthreads(); }
    float mu = red[0] / jb.dout;
    __syncthreads();
    float d = (t < jb.dout) ? (hv - mu) : 0.f;
    red[t] = d * d;
    __syncthreads();
#pragma unroll
    for (int s = 128; s > 0; s >>= 1) { if (t < s) red[t] += red[t + s]; __syncthreads(); }
    float var = red[0] / jb.dout;
    float rstd = rsqrtf(var + 1e-5f);
    float y = 0.f;
    if (t < jb.dout) {
        y = d * rstd * jb.g[t] + jb.beta[t];
        if (jb.of32) jb.of32[(size_t)row * jb.ldo + t] = y;
        if (jb.obf)  jb.obf[(size_t)row * jb.ldob + t] = (bf16_t)y;
    } else if (jb.obf && t < jb.padN) {
        jb.obf[(size_t)row * jb.ldob + t] = (bf16_t)0.f;
    }
    if (jb.wo) {
        __syncthreads();
        red[t] = (t < jb.dout) ? y * jb.wo[t] : 0.f;
        __syncthreads();
#pragma unroll
        for (int s = 128; s > 0; s >>= 1) { if (t < s) red[t] += red[t + s]; __syncthreads(); }
        if (t == 0) jb.praw[row] = red[0] + jb.bo[0];
    }
}

// --------- sparse transition (7 neighbors) + fused prior logsumexp ---------
__global__ __launch_bounds__(256) void trans_k(const float* __restrict__ hin,
                                               const float* __restrict__ hout,
                                               float* __restrict__ tr,
                                               const float* __restrict__ praw,
                                               float* __restrict__ plse)
{
    __shared__ float red[256];
    if (blockIdx.x == 512) {
        int t = threadIdx.x;
        float v[8];
        float m = -INFINITY;
#pragma unroll
        for (int i = 0; i < 8; i++) { v[i] = praw[t * 8 + i]; m = fmaxf(m, v[i]); }
        red[t] = m;
        __syncthreads();
#pragma unroll
        for (int s = 128; s > 0; s >>= 1) { if (t < s) red[t] = fmaxf(red[t], red[t + s]); __syncthreads(); }
        float M = red[0];
        __syncthreads();
        float ss = 0.f;
#pragma unroll
        for (int i = 0; i < 8; i++) ss += __expf(v[i] - M);
        red[t] = ss;
        __syncthreads();
#pragma unroll
        for (int s = 128; s > 0; s >>= 1) { if (t < s) red[t] += red[t + s]; __syncthreads(); }
        if (t == 0) plse[0] = M + __logf(red[0]);
        return;
    }
    const int OFFS[7] = {0, 1, -1, 16, -16, 256, 512};
    int j = blockIdx.x * 4 + (threadIdx.x >> 6);
    int lane = threadIdx.x & 63;
    float4 a = ((const float4*)(hin + (size_t)j * 256))[lane];
    float d[7];
#pragma unroll
    for (int k = 0; k < 7; k++) {
        int i = j + OFFS[k];
        float pdot = 0.f;
        if ((unsigned)i < 2048u) {
            float4 b = ((const float4*)(hout + (size_t)i * 256))[lane];
            pdot = a.x * b.x + a.y * b.y + a.z * b.z + a.w * b.w;
        }
#pragma unroll
        for (int o = 32; o > 0; o >>= 1) pdot += __shfl_down(pdot, o);
        d[k] = pdot;
    }
    if (lane == 0) {
        float m = -INFINITY;
#pragma unroll
        for (int k = 0; k < 7; k++) { int i = j + OFFS[k]; if ((unsigned)i < 2048u) m = fmaxf(m, d[k]); }
        float ss = 0.f;
#pragma unroll
        for (int k = 0; k < 7; k++) { int i = j + OFFS[k]; if ((unsigned)i < 2048u) ss += __expf(d[k] - m); }
        float l = __logf(ss);
#pragma unroll
        for (int k = 0; k < 7; k++) {
            int i = j + OFFS[k];
            tr[(size_t)j * 8 + k] = ((unsigned)i < 2048u) ? (d[k] - m - l) : -INFINITY;
        }
        tr[(size_t)j * 8 + 7] = -INFINITY;
    }
}

// ------------- emission LSE GEMM v3: LDS-free, fragment-direct -------------
// A = hemit bf16 [2048 x 128]; B = tok_bf bf16 [10112 x 128] (zero-padded).
// Per block: 128 m-rows x 128 n-rows; 4 waves in 2x2; per-wave 4x4 frags.
// Fragments loaded straight from global (operands are L2-resident).
__global__ __launch_bounds__(256) void lse_gemm_k(
    const bf16_t* __restrict__ hemit, const bf16_t* __restrict__ tok_bf,
    float* __restrict__ Pmax, float* __restrict__ Psum)
{
    __shared__ float pmS[2][128];
    __shared__ float psS[2][128];
    const int mb = blockIdx.x * 128;
    const int n0 = blockIdx.y * 128;
    const int tid  = threadIdx.x;
    const int lane = tid & 63, wave = tid >> 6;
    const int wm = (wave & 1) * 64, wn = (wave >> 1) * 64;
    const int qm = lane & 15, q = lane >> 4;

    floatx4 acc[4][4];
    floatx4 zf = {0.f, 0.f, 0.f, 0.f};
#pragma unroll
    for (int i = 0; i < 4; i++)
#pragma unroll
        for (int j = 0; j < 4; j++) acc[i][j] = zf;

    const bf16_t* Aw = hemit  + (size_t)(mb + wm + qm) * 128 + q * 8;
    const bf16_t* Bw = tok_bf + (size_t)(n0 + wn + qm) * 128 + q * 8;

#pragma unroll
    for (int kk = 0; kk < 4; kk++) {
        bf16x8 a[4], b[4];
#pragma unroll
        for (int i = 0; i < 4; i++) a[i] = *(const bf16x8*)&Aw[(size_t)(i * 16) * 128 + kk * 32];
#pragma unroll
        for (int i = 0; i < 4; i++) b[i] = *(const bf16x8*)&Bw[(size_t)(i * 16) * 128 + kk * 32];
#pragma unroll
        for (int mi = 0; mi < 4; mi++)
#pragma unroll
            for (int ni = 0; ni < 4; ni++)
                acc[mi][ni] = __builtin_amdgcn_mfma_f32_16x16x32_bf16(a[mi], b[ni], acc[mi][ni], 0, 0, 0);
    }

    // per-row (max, sumexp) over this wave's 64 cols, shuffle-reduced
    const int cl = lane & 15, rq = (lane >> 4) * 4;
    const int half = wn >> 6;
#pragma unroll
    for (int mi = 0; mi < 4; mi++) {
#pragma unroll
        for (int r = 0; r < 4; r++) {
            float mm = -INFINITY;
#pragma unroll
            for (int ni = 0; ni < 4; ni++) {
                int gcol = n0 + wn + ni * 16 + cl;
                if (gcol < 10000) mm = fmaxf(mm, acc[mi][ni][r]);
            }
            mm = fmaxf(mm, __shfl_xor(mm, 1));
            mm = fmaxf(mm, __shfl_xor(mm, 2));
            mm = fmaxf(mm, __shfl_xor(mm, 4));
            mm = fmaxf(mm, __shfl_xor(mm, 8));
            float ss = 0.f;
#pragma unroll
            for (int ni = 0; ni < 4; ni++) {
                int gcol = n0 + wn + ni * 16 + cl;
                if (gcol < 10000) ss += __expf(acc[mi][ni][r] - mm);
            }
            ss += __shfl_xor(ss, 1);
            ss += __shfl_xor(ss, 2);
            ss += __shfl_xor(ss, 4);
            ss += __shfl_xor(ss, 8);
            if (cl == 0) {
                int row = wm + mi * 16 + rq + r;
                pmS[half][row] = mm;
                psS[half][row] = ss;
            }
        }
    }
    __syncthreads();
    if (tid < 128) {
        float ma = pmS[0][tid], mb2 = pmS[1][tid];
        float M = fmaxf(ma, mb2);
        float S = psS[0][tid] * __expf(ma - M) + psS[1][tid] * __expf(mb2 - M);
        Pmax[(size_t)(mb + tid) * LSE_LD + blockIdx.y] = M;
        Psum[(size_t)(mb + tid) * LSE_LD + blockIdx.y] = S;
    }
}

// --------------------- emission logsumexp finalize (wave/state) ------------
__global__ __launch_bounds__(256) void lse_fin_k(const float* __restrict__ Pmax,
                                                 const float* __restrict__ Psum,
                                                 float* __restrict__ lse)
{
    int s = (blockIdx.x * 256 + threadIdx.x) >> 6;   // one wave per state
    int lane = threadIdx.x & 63;
    const float* pm = Pmax + (size_t)s * LSE_LD;
    const float* ps = Psum + (size_t)s * LSE_LD;
    float pv[2], sv[2];
    float m = -INFINITY;
#pragma unroll
    for (int i = 0; i < 2; i++) {
        int nb = i * 64 + lane;
        bool ok = nb < NT2;
        pv[i] = ok ? pm[nb] : -INFINITY;
        sv[i] = ok ? ps[nb] : 0.f;
        m = fmaxf(m, pv[i]);
    }
#pragma unroll
    for (int o = 1; o < 64; o <<= 1) m = fmaxf(m, __shfl_xor(m, o));
    float ss = 0.f;
#pragma unroll
    for (int i = 0; i < 2; i++) if (sv[i] > 0.f) ss += sv[i] * __expf(pv[i] - m);
#pragma unroll
    for (int o = 1; o < 64; o <<= 1) ss += __shfl_xor(ss, o);
    if (lane == 0) lse[s] = m + __logf(ss);
}

// ---- fused: em tile MFMA (12 tokens x 256 states) + 5x5 pool + emis -------
#define ELDT 136
__global__ __launch_bounds__(256) void empool_k(
    const float* __restrict__ tok_emb, const int* __restrict__ stories,
    const bf16_t* __restrict__ hemit, const float* __restrict__ lse,
    float* __restrict__ emis)
{
    __shared__ alignas(16) bf16_t As[16 * ELDT];
    __shared__ float Cs[16][260];
    __shared__ float sm2[256];
    __shared__ int stok[12];
    const int bt = blockIdx.x, z = blockIdx.y, t = threadIdx.x;
    if (t < 12) stok[t] = stories[bt * 12 + t];
    __syncthreads();
    {
        int row = t >> 4, c0 = (t & 15) * 8;
        int tok = (row < 12) ? stok[row] : 10000;
        const float* src = tok_emb + (size_t)tok * 100;
#pragma unroll
        for (int c = 0; c < 8; c++) {
            int cc = c0 + c;
            float v = (tok < 10000 && cc < 100) ? src[cc] : 0.f;
            As[row * ELDT + cc] = (bf16_t)v;
        }
    }
    __syncthreads();

    const int lane = t & 63, wave = t >> 6;
    const int qm = lane & 15, q = lane >> 4;
    floatx4 acc[4];
    floatx4 zf = {0.f, 0.f, 0.f, 0.f};
#pragma unroll
    for (int j = 0; j < 4; j++) acc[j] = zf;

#pragma unroll
    for (int kk = 0; kk < 4; kk++) {
        bf16x8 a = *(const bf16x8*)&As[qm * ELDT + kk * 32 + q * 8];
#pragma unroll
        for (int j = 0; j < 4; j++) {
            int nrow = z * 256 + (wave * 4 + j) * 16 + qm;
            bf16x8 b = *(const bf16x8*)&hemit[(size_t)nrow * 128 + kk * 32 + q * 8];
            acc[j] = __builtin_amdgcn_mfma_f32_16x16x32_bf16(a, b, acc[j], 0, 0, 0);
        }
    }
    {
        const int cl = lane & 15, rq = (lane >> 4) * 4;
#pragma unroll
        for (int j = 0; j < 4; j++) {
            int n = (wave * 4 + j) * 16 + cl;
            float ls = lse[z * 256 + n];
#pragma unroll
            for (int r = 0; r < 4; r++)
                Cs[rq + r][n] = acc[j][r] - ls;
        }
    }
    __syncthreads();

    const int a = t >> 4, b = t & 15;
    float accum = 0.f;
    for (int l = 0; l < 12; l++) {
        float m = -INFINITY;
#pragma unroll
        for (int d = -2; d <= 2; d++) {
            int bb = b + d; bb = bb < 0 ? 0 : (bb > 15 ? 15 : bb);
            m = fmaxf(m, Cs[l][a * 16 + bb]);
        }
        float ss = 0.f;
#pragma unroll
        for (int d = -2; d <= 2; d++) {
            int bb = b + d; bb = bb < 0 ? 0 : (bb > 15 ? 15 : bb);
            ss += __expf(Cs[l][a * 16 + bb] - m);
        }
        sm2[t] = m + __logf(ss);
        __syncthreads();
        float m2 = -INFINITY;
#pragma unroll
        for (int d = -2; d <= 2; d++) {
            int aa = a + d; aa = aa < 0 ? 0 : (aa > 15 ? 15 : aa);
            m2 = fmaxf(m2, sm2[aa * 16 + b]);
        }
        float s2 = 0.f;
#pragma unroll
        for (int d = -2; d <= 2; d++) {
            int aa = a + d; aa = aa < 0 ? 0 : (aa > 15 ? 15 : aa);
            s2 += __expf(sm2[aa * 16 + b] - m2);
        }
        if (stok[l] < 10000) accum += m2 + __logf(s2) - 3.2188758248682006f;  // log(25)
        __syncthreads();
    }
    emis[(size_t)bt * S_TOT + (size_t)z * 256 + t] = accum;
}

// --------------------- HMM forward recursion -------------------------------
__global__ __launch_bounds__(1024) void fwd_k(const float* __restrict__ emm,
                                              const float* __restrict__ praw,
                                              const float* __restrict__ plse,
                                              const float* __restrict__ tr,
                                              float* __restrict__ out)
{
    const int OFFS[7] = {0, 1, -1, 16, -16, 256, 512};
    __shared__ float sc[2][S_TOT];
    int b = blockIdx.x, t = threadIdx.x;
    float pl = plse[0];
    const float* eb = emm + (size_t)b * 16 * S_TOT;

    float e[2][16];
#pragma unroll
    for (int i = 0; i < 2; i++) {
        int j = i * 1024 + t;
#pragma unroll
        for (int tt = 0; tt < 16; tt++) e[i][tt] = eb[tt * S_TOT + j];
    }
    float trj[2][7];
#pragma unroll
    for (int i = 0; i < 2; i++) {
        int j = i * 1024 + t;
        float4 lo = ((const float4*)(tr + (size_t)j * 8))[0];
        float4 hi = ((const float4*)(tr + (size_t)j * 8))[1];
        trj[i][0] = lo.x; trj[i][1] = lo.y; trj[i][2] = lo.z; trj[i][3] = lo.w;
        trj[i][4] = hi.x; trj[i][5] = hi.y; trj[i][6] = hi.z;
    }
#pragma unroll
    for (int i = 0; i < 2; i++) {
        int j = i * 1024 + t;
        float v = e[i][0] + praw[j] - pl;
        sc[0][j] = v;
        out[(size_t)b * S_TOT + j] = v;
    }
    __syncthreads();
#pragma unroll
    for (int tt = 1; tt < 16; tt++) {
        int cur = tt & 1, prv = cur ^ 1;
#pragma unroll
        for (int i = 0; i < 2; i++) {
            int j = i * 1024 + t;
            float x[7];
            float m = -INFINITY;
#pragma unroll
            for (int k = 0; k < 7; k++) {
                int ii = j + OFFS[k];
                ii = ii < 0 ? 0 : (ii > 2047 ? 2047 : ii);
                x[k] = trj[i][k] + sc[prv][ii];
                m = fmaxf(m, x[k]);
            }
            float ss = 0.f;
#pragma unroll
            for (int k = 0; k < 7; k++) ss += __expf(x[k] - m);
            float v = e[i][tt] + m + __logf(ss);
            sc[cur][j] = v;
            out[(size_t)tt * (8 * S_TOT) + (size_t)b * S_TOT + j] = v;
        }
        __syncthreads();
    }
}

// ---------------------------------------------------------------------------
extern "C" void kernel_launch(void* const* d_in, const int* in_sizes, int n_in,
                              void* d_out, int out_size, void* d_ws, size_t ws_size,
                              hipStream_t stream)
{
    (void)in_sizes; (void)n_in; (void)out_size; (void)ws_size;
    const float* state_emb  = (const float*)d_in[0];
    const float* tok_emb    = (const float*)d_in[1];
    const float* start_w1   = (const float*)d_in[2];
    const float* start_b1   = (const float*)d_in[3];
    const float* start_w2   = (const float*)d_in[4];
    const float* start_b2   = (const float*)d_in[5];
    const float* start_g    = (const float*)d_in[6];
    const float* start_beta = (const float*)d_in[7];
    const float* start_wo   = (const float*)d_in[8];
    const float* start_bo   = (const float*)d_in[9];
    const float* tin_w1     = (const float*)d_in[10];
    const float* tin_b1     = (const float*)d_in[11];
    const float* tin_w2     = (const float*)d_in[12];
    const float* tin_b2     = (const float*)d_in[13];
    const float* tin_g      = (const float*)d_in[14];
    const float* tin_beta   = (const float*)d_in[15];
    const float* tout_w1    = (const float*)d_in[16];
    const float* tout_b1    = (const float*)d_in[17];
    const float* tout_w2    = (const float*)d_in[18];
    const float* tout_b2    = (const float*)d_in[19];
    const float* tout_g     = (const float*)d_in[20];
    const float* tout_beta  = (const float*)d_in[21];
    const float* emit_w1    = (const float*)d_in[22];
    const float* emit_b1    = (const float*)d_in[23];
    const float* emit_w2    = (const float*)d_in[24];
    const float* emit_b2    = (const float*)d_in[25];
    const float* emit_g     = (const float*)d_in[26];
    const float* emit_beta  = (const float*)d_in[27];
    const int*   stories    = (const int*)d_in[28];
    float* out = (float*)d_out;

    char* base = (char*)d_ws;
    size_t off = 0;
    auto carve = [&](size_t bytes) -> char* {
        char* r = base + off;
        off = (off + bytes + 255) & ~(size_t)255;
        return r;
    };

    // ---- persistent region ----
    bf16_t* hemit  = (bf16_t*)carve((size_t)2048 * 128 * 2);
    bf16_t* tok_bf = (bf16_t*)carve((size_t)VPAD * 128 * 2);
    float*  hin    = (float*)carve((size_t)2048 * 256 * 4);
    float*  hout   = (float*)carve((size_t)2048 * 256 * 4);
    float*  praw   = (float*)carve((size_t)2048 * 4);
    float*  plse   = (float*)carve(256);
    float*  trans  = (float*)carve((size_t)2048 * 8 * 4);
    float*  pmax   = (float*)carve((size_t)2048 * LSE_LD * 4);
    float*  psum   = (float*)carve((size_t)2048 * LSE_LD * 4);
    float*  lse    = (float*)carve((size_t)2048 * 4);
    float*  emis   = (float*)carve((size_t)128 * 2048 * 4);

    // ---- stage-1/2 temps ----
    float*  x1f_s  = (float*)carve((size_t)2048 * 256 * 4);
    float*  x1f_i  = (float*)carve((size_t)2048 * 256 * 4);
    float*  x1f_o  = (float*)carve((size_t)2048 * 256 * 4);
    float*  x1f_e  = (float*)carve((size_t)2048 * 128 * 4);
    bf16_t* x1b_s  = (bf16_t*)carve((size_t)2048 * 256 * 2);
    bf16_t* x1b_i  = (bf16_t*)carve((size_t)2048 * 256 * 2);
    bf16_t* x1b_o  = (bf16_t*)carve((size_t)2048 * 256 * 2);
    bf16_t* x1b_e  = (bf16_t*)carve((size_t)2048 * 128 * 2);
    float*  htmp_s = (float*)carve((size_t)2048 * 256 * 4);
    float*  htmp_i = (float*)carve((size_t)2048 * 256 * 4);
    float*  htmp_o = (float*)carve((size_t)2048 * 256 * 4);
    float*  htmp_e = (float*)carve((size_t)2048 * 128 * 4);

    // 0. tok_emb -> padded bf16 (coalesced)
    tokconv_k<<<(VPAD * 128) / 256, 256, 0, stream>>>(tok_emb, tok_bf);

    // 1. stage-1 batched GEMM: x1 = relu(state_emb @ W1^T + b1)  (A,B f32)
    GJobs g1;
    g1.j[0] = {state_emb, nullptr, 256, start_w1, 256, 256, 256, 256, 256, x1f_s, 256, start_b1, 256, nullptr, 0, x1b_s, 256};
    g1.j[1] = {state_emb, nullptr, 256, tin_w1,   256, 256, 256, 256, 256, x1f_i, 256, tin_b1,   256, nullptr, 0, x1b_i, 256};
    g1.j[2] = {state_emb, nullptr, 256, tout_w1,  256, 256, 256, 256, 256, x1f_o, 256, tout_b1,  256, nullptr, 0, x1b_o, 256};
    g1.j[3] = {state_emb, nullptr, 256, emit_w1,  256, 128, 100, 256, 256, x1f_e, 128, emit_b1,  100, nullptr, 0, x1b_e, 128};
    gemm_k<1, 1><<<dim3(32, 4, 4), 256, 0, stream>>>(g1);

    // 2. stage-2 batched GEMM: h = relu(x1 @ W2^T + b2) + x1  (A bf16, B f32)
    GJobs g2;
    g2.j[0] = {nullptr, x1b_s, 256, start_w2, 256, 256, 256, 256, 256, htmp_s, 256, start_b2, 256, x1f_s, 256, nullptr, 0};
    g2.j[1] = {nullptr, x1b_i, 256, tin_w2,   256, 256, 256, 256, 256, htmp_i, 256, tin_b2,   256, x1f_i, 256, nullptr, 0};
    g2.j[2] = {nullptr, x1b_o, 256, tout_w2,  256, 256, 256, 256, 256, htmp_o, 256, tout_b2,  256, x1f_o, 256, nullptr, 0};
    g2.j[3] = {nullptr, x1b_e, 128, emit_w2,  100, 128, 100, 128, 100, htmp_e, 128, emit_b2,  100, x1f_e, 128, nullptr, 0};
    gemm_k<2, 0><<<dim3(32, 4, 4), 256, 0, stream>>>(g2);

    // 3. batched LN (+ fused priors dot for start chain)
    LJobs lj;
    lj.j[0] = {htmp_s, 256, 256, start_g, start_beta, nullptr, 0, nullptr, 0, 0, start_wo, start_bo, praw};
    lj.j[1] = {htmp_i, 256, 256, tin_g,   tin_beta,   hin, 256, nullptr, 0, 0, nullptr, nullptr, nullptr};
    lj.j[2] = {htmp_o, 256, 256, tout_g,  tout_beta,  hout, 256, nullptr, 0, 0, nullptr, nullptr, nullptr};
    lj.j[3] = {htmp_e, 128, 100, emit_g,  emit_beta,  nullptr, 0, hemit, 128, 128, nullptr, nullptr, nullptr};
    ln_k<<<dim3(2048, 4), 256, 0, stream>>>(lj);

    // 4. transition log-softmax + prior LSE (fused, block 512)
    trans_k<<<513, 256, 0, stream>>>(hin, hout, trans, praw, plse);

    // 5. emission logsumexp over V=10000 (LDS-free fragment GEMM) + finalize
    lse_gemm_k<<<dim3(16, NT2), 256, 0, stream>>>(hemit, tok_bf, pmax, psum);
    lse_fin_k<<<512, 256, 0, stream>>>(pmax, psum, lse);

    // 6. fused em-GEMM + pool + emis
    empool_k<<<dim3(128, 8), 256, 0, stream>>>(tok_emb, stories, hemit, lse, emis);

    // 7. forward recursion -> [T,B,S] output
    fwd_k<<<8, 1024, 0, stream>>>(emis, praw, plse, trans, out);
}